// Round 1
// baseline (550.773 us; speedup 1.0000x reference)
//
#include <hip/hip_runtime.h>

#define D_MODEL 2048
#define SEQ     2048
#define BATCH   4
#define MTOT    (BATCH * SEQ)   // 8192
#define NQKV    (3 * D_MODEL)   // 6144

typedef __attribute__((ext_vector_type(8))) short bf16x8;
typedef __attribute__((ext_vector_type(8))) unsigned short ushort8;
typedef __attribute__((ext_vector_type(4))) float floatx4;

__device__ __forceinline__ unsigned short f2b(float f) {
    unsigned x = __builtin_bit_cast(unsigned, f);
    x += 0x7fffu + ((x >> 16) & 1u);   // round-to-nearest-even
    return (unsigned short)(x >> 16);
}

__device__ __forceinline__ void storeC(float* p, float v) { *p = v; }
__device__ __forceinline__ void storeC(unsigned short* p, float v) { *p = f2b(v); }

__device__ __forceinline__ void gload_lds16(const void* g, void* l) {
    __builtin_amdgcn_global_load_lds(
        (const __attribute__((address_space(1))) void*)g,
        (__attribute__((address_space(3))) void*)l,
        16, 0, 0);
}

// ---------------------------------------------------------------------------
// 256x256 8-phase BT GEMM (z-batched): C[m,n] = sum_k A[m,k]*B[n,k] (+bias)(*scale)
// A,B bf16 k-major. BK=64, 8 waves (2M x 4N), per-wave C = 128x64.
// Template per cdna_hip_programming.md §5 (m201): counted vmcnt (never 0 in
// steady loop), raw s_barrier, LDS XOR-swizzle via pre-swizzled global source
// (global_load_lds dest must stay linear), setprio around MFMA cluster.
// Phase q (q=0..3) computes mi-quarter {2q,2q+1} x all ni x ks; B fragments
// loaded once per K-tile (phase 1) and held in regs.
// Buffer death schedule: B halves die after ph1; A half0 after ph2; A half1
// after ph4. Staging (1 half-tile = 2 global_load_lds per phase):
//   ph1: A1(kt+1)->slot^1   ph2: B0(kt+2)->slot   ph3: B1(kt+2)->slot
//   ph4: A0(kt+2)->slot
// Waits: vmcnt(10) end-ph2 (A1(kt) landed), vmcnt(8) end-ph4 (B+A0(kt+1)
// landed); 4 half-tiles (8 loads) stay in flight. Requires NK >= 3.
// NOTE: default raster, no XCD swizzle (R4: swizzle tripled FETCH here).
// ---------------------------------------------------------------------------
#define PH_MFMA(q)                                                            \
    __builtin_amdgcn_s_barrier();                                             \
    asm volatile("s_waitcnt lgkmcnt(0)" ::: "memory");                        \
    __builtin_amdgcn_sched_barrier(0);                                        \
    __builtin_amdgcn_s_setprio(1);                                            \
    _Pragma("unroll") for (int ks = 0; ks < 2; ++ks)                          \
    _Pragma("unroll") for (int mi = 0; mi < 2; ++mi)                          \
    _Pragma("unroll") for (int ni = 0; ni < 4; ++ni)                          \
        acc[(q) * 2 + mi][ni] = __builtin_amdgcn_mfma_f32_16x16x32_bf16(      \
            af[mi][ks], bf[ni][ks], acc[(q) * 2 + mi][ni], 0, 0, 0);          \
    __builtin_amdgcn_s_setprio(0);

template <int EPI, typename CT>
__global__ __launch_bounds__(512, 2) void gemm256(
    const unsigned short* __restrict__ A, int lda, long long strA,
    const unsigned short* __restrict__ B, int ldb, long long strB,
    CT* __restrict__ C, int ldc, long long strC,
    int K, const float* __restrict__ bias, float scale)
{
    // [slot][half][128 rows x 64 k] each; 64 KiB A + 64 KiB B = 128 KiB
    __shared__ __align__(16) unsigned short As[2][2][128 * 64];
    __shared__ __align__(16) unsigned short Bs[2][2][128 * 64];

    const int t = threadIdx.x;
    const int w = t >> 6, l = t & 63;
    const int wg_m = w >> 2, wg_n = w & 3;       // 2 x 4 wave grid
    const int quad = l >> 4, r16 = l & 15, sw = l & 7;

    const int bz = blockIdx.z;
    A += (long long)bz * strA;
    B += (long long)bz * strB;
    C += (long long)bz * strC;

    const long long tM = (long long)blockIdx.y * 256;
    const long long tN = (long long)blockIdx.x * 256;

    // staging: thread t -> LDS chunk c = j*512 + t (j=0,1), row r = c>>3,
    // slot s = t&7. LDS(r,s) holds global k-chunk s^(r&7) (involution).
    const int r0 = t >> 3;
    const int kx = ((t & 7) ^ (r0 & 7)) * 8;     // swizzled k elem offset

    // A half h: LDS row r -> global row tM + (r>>6)*128 + h*64 + (r&63)
    auto stageA = [&](int kt, int h, int sl) {
        const unsigned short* g0 = A + (tM + h * 64 + r0) * (long long)lda + kt * 64 + kx;
        unsigned short* d = &As[sl][h][w * 512];         // wave-uniform base
        gload_lds16(g0, d);
        gload_lds16(g0 + 128ll * lda, d + 4096);
    };
    // B half h: LDS row r -> global row tN + h*128 + r
    auto stageB = [&](int kt, int h, int sl) {
        const unsigned short* g0 = B + (tN + h * 128 + r0) * (long long)ldb + kt * 64 + kx;
        unsigned short* d = &Bs[sl][h][w * 512];
        gload_lds16(g0, d);
        gload_lds16(g0 + 64ll * ldb, d + 4096);
    };

    bf16x8 bf[4][2], af[2][2];
    auto loadA = [&](int sl, int q) {
        const unsigned short* base = &As[sl][q >> 1][0];
        const int rb = wg_m * 64 + (q & 1) * 32;
#pragma unroll
        for (int mi = 0; mi < 2; ++mi)
#pragma unroll
            for (int ks = 0; ks < 2; ++ks)
                af[mi][ks] = *(const bf16x8*)
                    &base[(rb + mi * 16 + r16) * 64 + ((ks * 4 + quad) ^ sw) * 8];
    };
    auto loadB = [&](int sl) {
        const unsigned short* base = &Bs[sl][wg_n >> 1][0];
        const int rb = (wg_n & 1) * 64;
#pragma unroll
        for (int ni = 0; ni < 4; ++ni)
#pragma unroll
            for (int ks = 0; ks < 2; ++ks)
                bf[ni][ks] = *(const bf16x8*)
                    &base[(rb + ni * 16 + r16) * 64 + ((ks * 4 + quad) ^ sw) * 8];
    };

    floatx4 acc[8][4];
#pragma unroll
    for (int i = 0; i < 8; ++i)
#pragma unroll
        for (int j = 0; j < 4; ++j)
            acc[i][j] = (floatx4){0.f, 0.f, 0.f, 0.f};

    const int NK = K >> 6;   // requires NK >= 3 (all call sites have K=2048)

    // prologue, steady-state issue order (virtual iters -2,-1)
    stageB(0, 0, 0); stageB(0, 1, 0); stageA(0, 0, 0); stageA(0, 1, 0);
    stageB(1, 0, 1); stageB(1, 1, 1); stageA(1, 0, 1);
    asm volatile("s_waitcnt vmcnt(8)" ::: "memory");   // B(0)+A0(0) landed
    __builtin_amdgcn_s_barrier();

    for (int kt = 0; kt < NK; ++kt) {
        const int sl = kt & 1, so = sl ^ 1;

        // ---- phase 1 (q=0): B full + A quarter0 ----
        loadB(sl);
        loadA(sl, 0);
        if (kt + 1 < NK) stageA(kt + 1, 1, so);
        PH_MFMA(0)
        __builtin_amdgcn_s_barrier();

        // ---- phase 2 (q=1): A quarter1 ----
        loadA(sl, 1);
        if (kt + 2 < NK) stageB(kt + 2, 0, sl);
        PH_MFMA(1)
        if (kt < NK - 2) { asm volatile("s_waitcnt vmcnt(10)" ::: "memory"); }
        else             { asm volatile("s_waitcnt vmcnt(0)"  ::: "memory"); }
        __builtin_amdgcn_s_barrier();

        // ---- phase 3 (q=2): A quarter2 (half1, landed by vmcnt above) ----
        loadA(sl, 2);
        if (kt + 2 < NK) stageB(kt + 2, 1, sl);
        PH_MFMA(2)
        __builtin_amdgcn_s_barrier();

        // ---- phase 4 (q=3): A quarter3 ----
        loadA(sl, 3);
        if (kt + 2 < NK) stageA(kt + 2, 0, sl);
        PH_MFMA(3)
        if (kt < NK - 2) { asm volatile("s_waitcnt vmcnt(8)" ::: "memory"); }
        else             { asm volatile("s_waitcnt vmcnt(0)" ::: "memory"); }
        __builtin_amdgcn_s_barrier();
    }

    // C/D layout: col = lane&15, row = (lane>>4)*4 + reg
#pragma unroll
    for (int mi = 0; mi < 8; ++mi) {
#pragma unroll
        for (int ni = 0; ni < 4; ++ni) {
            const long long row = tM + wg_m * 128 + mi * 16 + quad * 4;
            const int col = (int)tN + wg_n * 64 + ni * 16 + r16;
            float badd = 0.f;
            if (EPI == 0) badd = bias[col];
#pragma unroll
            for (int r = 0; r < 4; ++r) {
                float v = acc[mi][ni][r] + badd;
                if (EPI == 1) v *= scale;
                storeC(&C[(row + r) * ldc + col], v);
            }
        }
    }
}

// f32 -> bf16 bulk convert, 8 elems/thread (n divisible by 2048)
__global__ void cvt_f32_bf16(const float* __restrict__ in,
                             unsigned short* __restrict__ out, long long n)
{
    long long i = ((long long)blockIdx.x * 256 + threadIdx.x) * 8;
    if (i + 7 < n) {
        float4 a = *(const float4*)(in + i);
        float4 b = *(const float4*)(in + i + 4);
        ushort8 o = {f2b(a.x), f2b(a.y), f2b(a.z), f2b(a.w),
                     f2b(b.x), f2b(b.y), f2b(b.z), f2b(b.w)};
        *(ushort8*)(out + i) = o;
    }
}

// W_qkv f32 [2048, 6144] (f = 3*d + sel fastest) -> Wqkv_t bf16 [6144, 2048],
// Wqkv_t[sel*2048 + d][k] = W_qkv[k][3*d + sel].  Tile: 64 k x 32 d (96 cols).
__global__ void deint_wqkv(const float* __restrict__ W,
                           unsigned short* __restrict__ Wt)
{
    __shared__ unsigned short t2[96][72];   // row stride 144B (16B-aligned)
    const int d0 = blockIdx.x * 32;
    const int k0 = blockIdx.y * 64;
    const int t = threadIdx.x;

#pragma unroll
    for (int it = 0; it < 24; ++it) {
        int i = t + it * 256;               // 0..6143 over 64 rows x 96 cols
        int r = i / 96, c = i - r * 96;
        t2[c][r] = f2b(W[(long long)(k0 + r) * NQKV + 3 * d0 + c]);
    }
    __syncthreads();

#pragma unroll
    for (int rnd = 0; rnd < 3; ++rnd) {
        int c  = (t >> 3) + rnd * 32;       // 0..95
        int kc = t & 7;
        int dx = c / 3, sel = c - 3 * dx;
        *(ushort8*)&Wt[(long long)(sel * 2048 + d0 + dx) * D_MODEL + k0 + kc * 8] =
            *(const ushort8*)&t2[c][kc * 8];
    }
}

// W_fc f32 [2048, 2048] -> Wfc_t bf16, Wfc_t[n][k] = W_fc[k][n]. Tile 64x64.
__global__ void transpose_wfc(const float* __restrict__ W,
                              unsigned short* __restrict__ Wt)
{
    __shared__ unsigned short t2[64][72];
    const int n0 = blockIdx.x * 64;
    const int k0 = blockIdx.y * 64;
    const int t = threadIdx.x;

#pragma unroll
    for (int it = 0; it < 16; ++it) {
        int i = t + it * 256;               // 64 rows x 64 cols
        int r = i >> 6, c = i & 63;
        t2[c][r] = f2b(W[(long long)(k0 + r) * D_MODEL + n0 + c]);
    }
    __syncthreads();

#pragma unroll
    for (int rnd = 0; rnd < 2; ++rnd) {
        int c  = (t >> 3) + rnd * 32;
        int kc = t & 7;
        *(ushort8*)&Wt[(long long)(n0 + c) * D_MODEL + k0 + kc * 8] =
            *(const ushort8*)&t2[c][kc * 8];
    }
}

// bias deinterleave (f32 -> f32): bias_qkv_t[sel*2048+d] = bqkv[3*d+sel]
__global__ void prep_bias(const float* __restrict__ bqkv,
                          const float* __restrict__ bfc,
                          float* __restrict__ bias_qkv_t,
                          float* __restrict__ bias_fc)
{
    int i = blockIdx.x * 256 + threadIdx.x;
    if (i < NQKV) {
        int sel = i >> 11, d = i & 2047;
        bias_qkv_t[i] = bqkv[3 * d + sel];
    } else if (i < NQKV + D_MODEL) {
        bias_fc[i - NQKV] = bfc[i - NQKV];
    }
}

extern "C" void kernel_launch(void* const* d_in, const int* in_sizes, int n_in,
                              void* d_out, int out_size, void* d_ws, size_t ws_size,
                              hipStream_t stream)
{
    (void)in_sizes; (void)n_in; (void)out_size;

    const float* x    = (const float*)d_in[0];
    const float* Wqkv = (const float*)d_in[1];
    const float* bqkv = (const float*)d_in[2];
    const float* Wfc  = (const float*)d_in[3];
    const float* bfc  = (const float*)d_in[4];
    float* out = (float*)d_out;

    char* ws = (char*)d_ws;
    size_t off = 0;
    auto alloc = [&](size_t bytes) {
        void* p = ws + off;
        off += (bytes + 255) & ~(size_t)255;
        return p;
    };

    const float scale = 0.02209708691207961f;  // 2048^-0.5
    const long long nx = (long long)MTOT * D_MODEL;  // 16.8M elems

    const size_t NEED_BATCHED = (size_t)(33554432ull + 8388608ull + 25165824ull
                                + 100663296ull + 33554432ull + 65536ull);

    if (ws_size >= NEED_BATCHED) {
        unsigned short* xb     = (unsigned short*)alloc((size_t)MTOT * D_MODEL * 2);
        unsigned short* Wfc_t  = (unsigned short*)alloc((size_t)D_MODEL * D_MODEL * 2);
        unsigned short* Wqkv_t = (unsigned short*)alloc((size_t)NQKV * D_MODEL * 2);
        unsigned short* QKV    = (unsigned short*)alloc((size_t)MTOT * NQKV * 2);
        unsigned short* S      = (unsigned short*)alloc((size_t)BATCH * SEQ * SEQ * 2);
        float* bias_qkv = (float*)alloc((size_t)NQKV * 4);
        float* bias_fc  = (float*)alloc((size_t)D_MODEL * 4);
        unsigned short* Abuf = xb;   // xb dead after stage 1

        cvt_f32_bf16<<<(int)(nx / 2048), 256, 0, stream>>>(x, xb, nx);
        deint_wqkv<<<dim3(64, 32), 256, 0, stream>>>(Wqkv, Wqkv_t);
        transpose_wfc<<<dim3(32, 32), 256, 0, stream>>>(Wfc, Wfc_t);
        prep_bias<<<32, 256, 0, stream>>>(bqkv, bfc, bias_qkv, bias_fc);

        const long long sQKV = (long long)SEQ * NQKV;
        const long long sS   = (long long)SEQ * SEQ;

        // 1) QKV = xb @ Wqkv_t^T + bias   [8192 x 6144]
        gemm256<0, unsigned short><<<dim3(NQKV / 256, MTOT / 256, 1), 512, 0, stream>>>(
            xb, D_MODEL, 0, Wqkv_t, D_MODEL, 0, QKV, NQKV, 0, D_MODEL, bias_qkv, 1.f);
        // 2) S_b = Q_b @ K_b^T * scale    z-batched [2048 x 2048] x4
        gemm256<1, unsigned short><<<dim3(SEQ / 256, SEQ / 256, BATCH), 512, 0, stream>>>(
            QKV, NQKV, sQKV, QKV + D_MODEL, NQKV, sQKV, S, SEQ, sS, D_MODEL, nullptr, scale);
        // 3) A_b = S_b @ V_b^T            z-batched [2048 x 2048] x4
        gemm256<2, unsigned short><<<dim3(SEQ / 256, SEQ / 256, BATCH), 512, 0, stream>>>(
            S, SEQ, sS, QKV + 2 * D_MODEL, NQKV, sQKV, Abuf, SEQ, sS, SEQ, nullptr, 1.f);
        // 4) out = A @ Wfc_t^T + bias_fc  [8192 x 2048] f32 out
        gemm256<0, float><<<dim3(D_MODEL / 256, MTOT / 256, 1), 512, 0, stream>>>(
            Abuf, SEQ, 0, Wfc_t, D_MODEL, 0, out, D_MODEL, 0, SEQ, bias_fc, 1.f);
    } else {
        // Fallback: per-batch (~110 MB)
        unsigned short* xb     = (unsigned short*)alloc((size_t)MTOT * D_MODEL * 2);
        unsigned short* Wqkv_t = (unsigned short*)alloc((size_t)NQKV * D_MODEL * 2);
        unsigned short* Wfc_t  = (unsigned short*)alloc((size_t)D_MODEL * D_MODEL * 2);
        unsigned short* QKVb   = (unsigned short*)alloc((size_t)SEQ * NQKV * 2);
        unsigned short* Sb     = (unsigned short*)alloc((size_t)SEQ * SEQ * 2);
        unsigned short* Ab     = (unsigned short*)alloc((size_t)SEQ * SEQ * 2);
        float* bias_qkv = (float*)alloc((size_t)NQKV * 4);
        float* bias_fc  = (float*)alloc((size_t)D_MODEL * 4);

        cvt_f32_bf16<<<(int)(nx / 2048), 256, 0, stream>>>(x, xb, nx);
        deint_wqkv<<<dim3(64, 32), 256, 0, stream>>>(Wqkv, Wqkv_t);
        transpose_wfc<<<dim3(32, 32), 256, 0, stream>>>(Wfc, Wfc_t);
        prep_bias<<<32, 256, 0, stream>>>(bqkv, bfc, bias_qkv, bias_fc);

        for (int b = 0; b < BATCH; ++b) {
            const unsigned short* xb_b = xb + (long long)b * SEQ * D_MODEL;
            float* out_b = out + (long long)b * SEQ * D_MODEL;
            gemm256<0, unsigned short><<<dim3(NQKV / 256, SEQ / 256, 1), 512, 0, stream>>>(
                xb_b, D_MODEL, 0, Wqkv_t, D_MODEL, 0, QKVb, NQKV, 0, D_MODEL, bias_qkv, 1.f);
            gemm256<1, unsigned short><<<dim3(SEQ / 256, SEQ / 256, 1), 512, 0, stream>>>(
                QKVb, NQKV, 0, QKVb + D_MODEL, NQKV, 0, Sb, SEQ, 0, D_MODEL, nullptr, scale);
            gemm256<2, unsigned short><<<dim3(SEQ / 256, SEQ / 256, 1), 512, 0, stream>>>(
                Sb, SEQ, 0, QKVb + 2 * D_MODEL, NQKV, 0, Ab, SEQ, 0, SEQ, nullptr, 1.f);
            gemm256<0, float><<<dim3(D_MODEL / 256, SEQ / 256, 1), 512, 0, stream>>>(
                Ab, SEQ, 0, Wfc_t, D_MODEL, 0, out_b, D_MODEL, 0, SEQ, bias_fc, 1.f);
        }
    }
}